// Round 1
// baseline (867.332 us; speedup 1.0000x reference)
//
#include <hip/hip_runtime.h>

// Decoder step: attention (Bahdanau) + 2-layer LSTM + vocab projection.
// B=64, S=1024, V=32000, D=H=E=A=1024, L=2.
//
// d_out (floats): logits[64*32000] | h_new[2*64*1024] | c_new[2*64*1024] | attn_w[64*1024]
// ws (floats), big path (needs 162,136,064 B):
//   x[64*2048]@0 | q@131072 | score@196608 | part@262144 (max 4,096,000)
//   ctxpart@4358144 (8*64*1024) | Wae_bf16@4882432 (1,048,576 ushorts) | enc_bf16@6979584
// bva dropped: softmax(score+bva)==softmax(score).
//
// R1 (this round): attn GEMM rewritten as 256x256x64 8-phase pipeline
// (T2 LDS XOR-swizzle + T3/T4 counted vmcnt + T5 setprio + T1 XCD swizzle).
// Old 128x256 2-barrier version ran 208us at MfmaUtil 29% / 1.7e7 bank conf.

typedef __attribute__((ext_vector_type(8))) __bf16 bf16x8;
typedef __attribute__((ext_vector_type(4))) __bf16 bf16x4v;
typedef __attribute__((ext_vector_type(4))) float f32x4;

#define GLOADLDS(g, l)                                                         \
  __builtin_amdgcn_global_load_lds(                                            \
      (const __attribute__((address_space(1))) unsigned int*)(g),              \
      (__attribute__((address_space(3))) unsigned int*)(l), 16, 0, 0)

__device__ __forceinline__ ushort4 cvt4(f32x4 v) {
  bf16x4v h = {(__bf16)v.x, (__bf16)v.y, (__bf16)v.z, (__bf16)v.w};  // RNE; native cvt_pk on gfx950
  union { bf16x4v h; ushort4 u; } c; c.h = h; return c.u;
}
__device__ __forceinline__ float bf2f(unsigned short u) {
  return __uint_as_float(((unsigned int)u) << 16);
}
__device__ __forceinline__ float sigm(float x) { return 1.0f / (1.0f + __expf(-x)); }
// exact at both limits: x->+inf => 1-0 ; x->-inf => 1-2 = -1
__device__ __forceinline__ float fast_tanh(float x) {
  return 1.0f - 2.0f / (__expf(2.0f * x) + 1.0f);
}

// fp32 -> bf16, 8 elements/thread; n8 = element_count / 8
__global__ __launch_bounds__(256) void cvt_bf_k(const float* __restrict__ in,
                                                unsigned short* __restrict__ out, int n8) {
  int i = blockIdx.x * 256 + threadIdx.x;
  if (i >= n8) return;
  const f32x4* p = (const f32x4*)in + 2 * (size_t)i;
  ushort4* o = (ushort4*)out + 2 * (size_t)i;
  f32x4 a = p[0], b = p[1];
  o[0] = cvt4(a);
  o[1] = cvt4(b);
}

// x[b][0:1024] = emb[input_step[b]]
__global__ __launch_bounds__(256) void gather_k(const int* __restrict__ step,
                                                const float* __restrict__ emb,
                                                float* __restrict__ x) {
  int b = blockIdx.x, t = threadIdx.x;
  int row = step[b];
  f32x4 v = *(const f32x4*)(emb + (size_t)row * 1024 + t * 4);
  *(f32x4*)(x + (size_t)b * 2048 + t * 4) = v;
}

// Split-K skinny GEMM, M=64, BN=256, fp32 in, bf16 staging via native casts.
__global__ __launch_bounds__(256) void small_gemm(
    const float* __restrict__ A0, int lda0,
    const float* __restrict__ A1, int lda1, int kSplitA,
    const float* __restrict__ B0, int ldb0,
    const float* __restrict__ B1, int ldb1, int kSplitB,
    float* __restrict__ part, int N, int kChunk) {
  __shared__ unsigned short As[64 * 32];
  __shared__ unsigned short Bs[256 * 32];
  int tid = threadIdx.x;
  int n0 = blockIdx.x * 256;
  int k0 = blockIdx.y * kChunk;
  int wave = tid >> 6, lane = tid & 63, quad = lane >> 4, l15 = lane & 15;
  f32x4 acc[4][4] = {};
  for (int kb = k0; kb < k0 + kChunk; kb += 32) {
    const float* Ap; int ldA, kA;
    if (kb < kSplitA) { Ap = A0; ldA = lda0; kA = kb; }
    else              { Ap = A1; ldA = lda1; kA = kb - kSplitA; }
    const float* Bp; int ldB, kB;
    if (kb < kSplitB) { Bp = B0; ldB = ldb0; kB = kb; }
    else              { Bp = B1; ldB = ldb1; kB = kb - kSplitB; }
#pragma unroll
    for (int c = 0; c < 2; c++) {               // A: 64x32
      int f = c * 256 + tid;
      int row = f >> 3, colf = f & 7;
      f32x4 v = *(const f32x4*)(Ap + (size_t)row * ldA + kA + colf * 4);
      *(ushort4*)&As[row * 32 + colf * 4] = cvt4(v);
    }
#pragma unroll
    for (int c = 0; c < 8; c++) {               // B: 256x32
      int f = c * 256 + tid;
      int row = f >> 3, colf = f & 7;
      f32x4 v = *(const f32x4*)(Bp + (size_t)(n0 + row) * ldB + kB + colf * 4);
      *(ushort4*)&Bs[row * 32 + colf * 4] = cvt4(v);
    }
    __syncthreads();
    bf16x8 af[4], bfv[4];
#pragma unroll
    for (int rt = 0; rt < 4; rt++)
      af[rt] = *(const bf16x8*)&As[(16 * rt + l15) * 32 + quad * 8];
#pragma unroll
    for (int ct = 0; ct < 4; ct++)
      bfv[ct] = *(const bf16x8*)&Bs[(64 * wave + 16 * ct + l15) * 32 + quad * 8];
#pragma unroll
    for (int rt = 0; rt < 4; rt++)
#pragma unroll
      for (int ct = 0; ct < 4; ct++)
        acc[rt][ct] = __builtin_amdgcn_mfma_f32_16x16x32_bf16(af[rt], bfv[ct], acc[rt][ct], 0, 0, 0);
    __syncthreads();
  }
  size_t base = (size_t)blockIdx.y * 64 * (size_t)N;
#pragma unroll
  for (int rt = 0; rt < 4; rt++)
#pragma unroll
    for (int ct = 0; ct < 4; ct++)
#pragma unroll
      for (int r = 0; r < 4; r++) {
        int m = 16 * rt + 4 * quad + r;
        int n = n0 + 64 * wave + 16 * ct + l15;
        part[base + (size_t)m * N + n] = acc[rt][ct][r];
      }
}

// q[b][a] = ba_h[a] + sum over 8 k-splits
__global__ __launch_bounds__(256) void q_reduce(const float* __restrict__ qpart,
                                                const float* __restrict__ ba_h,
                                                float* __restrict__ q) {
  int idx = blockIdx.x * 256 + threadIdx.x;
  int a = idx & 1023;
  float s = ba_h[a];
#pragma unroll
  for (int sp = 0; sp < 8; sp++) s += qpart[sp * 65536 + idx];
  q[idx] = s;
}

// ---------------------------------------------------------------------------
// 8-phase 256x256 bf16 attention GEMM, fused Bahdanau score epilogue.
// M=65536 N=1024 K=1024, BK=64, 512 thr = 8 waves (2M x 4N), 128x64 out/wave.
// LDS: 2 buffers x (A 32KB + B 32KB) = 128KB, column-XOR-swizzled
// (u ^= (u>>3)&0x38 in ushorts; involution; applied to staging SOURCE addr and
// ds_read addr, LDS dest stays linear per global_load_lds semantics).
// Per K-tile: 4 phases {ds_read subtile; [P3: stage tile c+2 (8 gloads) +
// s_waitcnt vmcnt(8)]; s_barrier; lgkmcnt(0); sched_barrier; setprio(1);
// 16 MFMA; setprio(0); s_barrier}. vmcnt never drains to 0 in steady state.
// ---------------------------------------------------------------------------

#define SCHED0() __builtin_amdgcn_sched_barrier(0)

#define STAGE_TILE(t)                                                        \
  {                                                                          \
    int _buf = (t) & 1;                                                      \
    const unsigned short* _as = encb + aSrc + (size_t)(t) * 64;              \
    const unsigned short* _bs = Waeb + bSrc + (size_t)(t) * 64;              \
    unsigned short* _la = &sh[_buf * 32768 + wave * 512];                    \
    unsigned short* _lb = &sh[_buf * 32768 + 16384 + wave * 512];            \
    GLOADLDS(_as,          _la);                                             \
    GLOADLDS(_as + 65536,  _la + 4096);                                      \
    GLOADLDS(_as + 131072, _la + 8192);                                      \
    GLOADLDS(_as + 196608, _la + 12288);                                     \
    GLOADLDS(_bs,          _lb);                                             \
    GLOADLDS(_bs + 65536,  _lb + 4096);                                      \
    GLOADLDS(_bs + 131072, _lb + 8192);                                      \
    GLOADLDS(_bs + 196608, _lb + 12288);                                     \
  }

#define LOAD_A(buf, mh)                                                      \
  {                                                                          \
    const unsigned short* _p = &sh[(buf) * 32768 + aRow + (mh) * 4096];      \
    _Pragma("unroll") for (int mr = 0; mr < 4; mr++) {                       \
      a[mr][0] = *(const bf16x8*)&_p[mr * 1024 + cs0];                       \
      a[mr][1] = *(const bf16x8*)&_p[mr * 1024 + cs1];                       \
    }                                                                        \
  }

#define LOAD_B(buf, nh, Bd)                                                  \
  {                                                                          \
    const unsigned short* _p = &sh[(buf) * 32768 + 16384 + bRow + (nh) * 2048]; \
    _Pragma("unroll") for (int nc = 0; nc < 2; nc++) {                       \
      Bd[nc][0] = *(const bf16x8*)&_p[nc * 1024 + cs0];                      \
      Bd[nc][1] = *(const bf16x8*)&_p[nc * 1024 + cs1];                      \
    }                                                                        \
  }

#define MMQ(mh, nh, Bd)                                                      \
  _Pragma("unroll") for (int mr = 0; mr < 4; mr++)                           \
  _Pragma("unroll") for (int nc = 0; nc < 2; nc++)                           \
  _Pragma("unroll") for (int ks = 0; ks < 2; ks++)                           \
    acc[(mh) * 4 + mr][(nh) * 2 + nc] = __builtin_amdgcn_mfma_f32_16x16x32_bf16( \
        a[mr][ks], Bd[nc][ks], acc[(mh) * 4 + mr][(nh) * 2 + nc], 0, 0, 0);

#define PH_WAIT_LGKM()                                                       \
  SCHED0();                                                                  \
  __builtin_amdgcn_s_barrier();                                              \
  asm volatile("s_waitcnt lgkmcnt(0)" ::: "memory");                         \
  SCHED0();

#define PH_END()                                                             \
  SCHED0();                                                                  \
  __builtin_amdgcn_s_barrier();                                              \
  SCHED0();

// MODE 0: steady (stage c+2, vmcnt(8));  1: vmcnt(0), no stage;  2: no wait.
#define GROUP(c, MODE)                                                       \
  {                                                                          \
    int buf = (c) & 1;                                                       \
    /* P0: A-half0 + B-half0 reads, compute quadrant (0,0) */                \
    LOAD_A(buf, 0);                                                          \
    LOAD_B(buf, 0, b0);                                                      \
    PH_WAIT_LGKM();                                                          \
    __builtin_amdgcn_s_setprio(1); MMQ(0, 0, b0); __builtin_amdgcn_s_setprio(0); \
    PH_END();                                                                \
    /* P1: B-half1 reads, quadrant (0,1) */                                  \
    LOAD_B(buf, 1, b1);                                                      \
    PH_WAIT_LGKM();                                                          \
    __builtin_amdgcn_s_setprio(1); MMQ(0, 1, b1); __builtin_amdgcn_s_setprio(0); \
    PH_END();                                                                \
    /* P2: A-half1 reads, quadrant (1,0) */                                  \
    LOAD_A(buf, 1);                                                          \
    PH_WAIT_LGKM();                                                          \
    __builtin_amdgcn_s_setprio(1); MMQ(1, 0, b0); __builtin_amdgcn_s_setprio(0); \
    PH_END();                                                                \
    /* P3: stage tile c+2 into this buffer (all reads of it done), wait on   \
       tile c+1 only (vmcnt(8) = allow the 8 just-issued to stay in flight) */ \
    if ((MODE) == 0) { STAGE_TILE((c) + 2); }                                \
    if ((MODE) == 0) asm volatile("s_waitcnt vmcnt(8)" ::: "memory");        \
    if ((MODE) == 1) asm volatile("s_waitcnt vmcnt(0)" ::: "memory");        \
    SCHED0();                                                                \
    __builtin_amdgcn_s_barrier();                                            \
    SCHED0();                                                                \
    __builtin_amdgcn_s_setprio(1); MMQ(1, 1, b1); __builtin_amdgcn_s_setprio(0); \
    PH_END();                                                                \
  }

__global__ __launch_bounds__(512, 2) void attn_gemm_8p(
    const unsigned short* __restrict__ encb, const unsigned short* __restrict__ Waeb,
    const float* __restrict__ q, const float* __restrict__ ba_e,
    const float* __restrict__ va, float* __restrict__ score) {
  __shared__ unsigned short sh[65536];   // [2 bufs][A 16384 | B 16384] ushorts
  __shared__ float red[256];
  int tid = threadIdx.x;
  int wave = tid >> 6, lane = tid & 63, quad = lane >> 4, l15 = lane & 15;
  int wr = wave >> 2, wc = wave & 3;

  // XCD swizzle: hw linear id -> logical; 4 N-siblings of an M-tile land on
  // one XCD so the 512KB A-panel is fetched once into that XCD's L2.
  int h = blockIdx.y * 4 + blockIdx.x;          // 0..1023, x-fastest dispatch
  int lgc = (h & 7) * 128 + (h >> 3);           // bijective, 1024 % 8 == 0
  int m0 = (lgc >> 2) * 256, n0 = (lgc & 3) * 256;

  // Staging source (pre-swizzled): dest byte p = j*8192 + wave*1024 + lane*16
  // holds logical element at p ^ ((p>>3)&0x70)  (row unchanged; 16B slot
  // slot = (lane&7) ^ (lane>>3) since row&7 == lane>>3 here).
  int srow = wave * 8 + (lane >> 3);
  int sslot = ((lane & 7) ^ (lane >> 3)) * 8;
  size_t aSrc = (size_t)(m0 + srow) * 1024 + sslot;
  size_t bSrc = (size_t)(n0 + srow) * 1024 + sslot;

  // Fragment read offsets (ushorts): logical u = row*64 + ks*32 + quad*8,
  // swizzled u ^= (u>>3)&0x38  ==  slot' = (ks*4+quad) ^ (l15&7).
  int aRow = (wr * 128 + l15) * 64;
  int bRow = (wc * 64 + l15) * 64;
  int cs0 = (quad ^ (l15 & 7)) * 8;
  int cs1 = ((4 + quad) ^ (l15 & 7)) * 8;

  bf16x8 a[4][2], b0[2][2], b1[2][2];
  f32x4 acc[8][4] = {};

  // Prologue: stage tiles 0 and 1, wait for tile 0 (allow tile 1 in flight).
  STAGE_TILE(0);
  STAGE_TILE(1);
  asm volatile("s_waitcnt vmcnt(8)" ::: "memory");
  SCHED0();
  __builtin_amdgcn_s_barrier();
  SCHED0();

  for (int c = 0; c < 14; ++c) GROUP(c, 0);
  GROUP(14, 1);
  GROUP(15, 2);

  // ---- fused score epilogue: score[m] += sum_n va[n]*tanh(q+ba_e+C[m,n]) ----
  __syncthreads();
  if (tid < 256) red[tid] = 0.0f;
  __syncthreads();
  int b = m0 >> 10;
  float qe[4], vv[4];
#pragma unroll
  for (int j = 0; j < 4; j++) {
    int n = n0 + wc * 64 + j * 16 + l15;
    qe[j] = q[b * 1024 + n] + ba_e[n];
    vv[j] = va[n];
  }
#pragma unroll
  for (int i = 0; i < 8; i++)
#pragma unroll
    for (int r = 0; r < 4; r++) {
      float p = 0.0f;
#pragma unroll
      for (int j = 0; j < 4; j++)
        p += vv[j] * fast_tanh(qe[j] + acc[i][j][r]);
      p += __shfl_xor(p, 1); p += __shfl_xor(p, 2);
      p += __shfl_xor(p, 4); p += __shfl_xor(p, 8);
      if (l15 == 0) atomicAdd(&red[wr * 128 + i * 16 + quad * 4 + r], p);
    }
  __syncthreads();
  if (tid < 256) atomicAdd(&score[m0 + tid], red[tid]);
}

#undef GROUP
#undef PH_END
#undef PH_WAIT_LGKM
#undef MMQ
#undef LOAD_B
#undef LOAD_A
#undef STAGE_TILE
#undef SCHED0

// fallback fp32 attention GEMM (grid dim3(4,512), N-fastest)
__global__ __launch_bounds__(512) void attn_gemm_f32(
    const float* __restrict__ enc, const float* __restrict__ Wae,
    const float* __restrict__ q, const float* __restrict__ ba_e,
    const float* __restrict__ va, float* __restrict__ score) {
  __shared__ unsigned short As[128 * 32];
  __shared__ unsigned short Bs[256 * 32];
  __shared__ float red[128];
  int tid = threadIdx.x;
  int n0 = blockIdx.x * 256, m0 = blockIdx.y * 128;
  int wave = tid >> 6, lane = tid & 63, quad = lane >> 4, l15 = lane & 15;
  int wr = wave >> 2, wc = wave & 3;
  f32x4 acc[4][4] = {};
  for (int kb = 0; kb < 1024; kb += 32) {
#pragma unroll
    for (int c = 0; c < 2; c++) {
      int f = c * 512 + tid;
      int row = f >> 3, colf = f & 7;
      f32x4 v = *(const f32x4*)(enc + (size_t)(m0 + row) * 1024 + kb + colf * 4);
      *(ushort4*)&As[row * 32 + colf * 4] = cvt4(v);
    }
#pragma unroll
    for (int c = 0; c < 4; c++) {
      int f = c * 512 + tid;
      int row = f >> 3, colf = f & 7;
      f32x4 v = *(const f32x4*)(Wae + (size_t)(n0 + row) * 1024 + kb + colf * 4);
      *(ushort4*)&Bs[row * 32 + colf * 4] = cvt4(v);
    }
    __syncthreads();
    bf16x8 af[4], bfv[4];
#pragma unroll
    for (int rt = 0; rt < 4; rt++)
      af[rt] = *(const bf16x8*)&As[(64 * wr + 16 * rt + l15) * 32 + quad * 8];
#pragma unroll
    for (int ct = 0; ct < 4; ct++)
      bfv[ct] = *(const bf16x8*)&Bs[(64 * wc + 16 * ct + l15) * 32 + quad * 8];
#pragma unroll
    for (int rt = 0; rt < 4; rt++)
#pragma unroll
      for (int ct = 0; ct < 4; ct++)
        acc[rt][ct] = __builtin_amdgcn_mfma_f32_16x16x32_bf16(af[rt], bfv[ct], acc[rt][ct], 0, 0, 0);
    __syncthreads();
  }
  int b = m0 >> 10;
  if (tid < 128) red[tid] = 0.0f;
  __syncthreads();
  float qe[4], vv[4];
#pragma unroll
  for (int ct = 0; ct < 4; ct++) {
    int n = n0 + 64 * wc + 16 * ct + l15;
    qe[ct] = q[b * 1024 + n] + ba_e[n];
    vv[ct] = va[n];
  }
#pragma unroll
  for (int rt = 0; rt < 4; rt++)
#pragma unroll
    for (int r = 0; r < 4; r++) {
      float p = 0.0f;
#pragma unroll
      for (int ct = 0; ct < 4; ct++)
        p += vv[ct] * tanhf(qe[ct] + acc[rt][ct][r]);
      p += __shfl_xor(p, 1); p += __shfl_xor(p, 2);
      p += __shfl_xor(p, 4); p += __shfl_xor(p, 8);
      if (l15 == 0) atomicAdd(&red[64 * wr + 16 * rt + 4 * quad + r], p);
    }
  __syncthreads();
  if (tid < 128) atomicAdd(&score[m0 + tid], red[tid]);
}

__global__ __launch_bounds__(256) void softmax_k(const float* __restrict__ score,
                                                 float* __restrict__ attnw) {
  int b = blockIdx.x, tid = threadIdx.x;
  __shared__ float wred[4];
  float v[4];
  float mx = -1e30f;
#pragma unroll
  for (int i = 0; i < 4; i++) {
    v[i] = score[b * 1024 + tid + 256 * i];
    mx = fmaxf(mx, v[i]);
  }
  for (int off = 1; off < 64; off <<= 1) mx = fmaxf(mx, __shfl_xor(mx, off));
  int w = tid >> 6;
  if ((tid & 63) == 0) wred[w] = mx;
  __syncthreads();
  mx = fmaxf(fmaxf(wred[0], wred[1]), fmaxf(wred[2], wred[3]));
  float s = 0.0f;
#pragma unroll
  for (int i = 0; i < 4; i++) { v[i] = __expf(v[i] - mx); s += v[i]; }
  for (int off = 1; off < 64; off <<= 1) s += __shfl_xor(s, off);
  __syncthreads();
  if ((tid & 63) == 0) wred[w] = s;
  __syncthreads();
  s = wred[0] + wred[1] + wred[2] + wred[3];
  float inv = 1.0f / s;
#pragma unroll
  for (int i = 0; i < 4; i++) attnw[b * 1024 + tid + 256 * i] = v[i] * inv;
}

// context partial over s-chunks (bf16 enc): grid (64 b, 8 sc), thread owns 4 e
__global__ __launch_bounds__(256) void context_bf(const unsigned short* __restrict__ encb,
                                                  const float* __restrict__ attnw,
                                                  float* __restrict__ ctxpart) {
  int b = blockIdx.x, sc = blockIdx.y, tid = threadIdx.x;
  __shared__ float w[128];
  if (tid < 128) w[tid] = attnw[b * 1024 + sc * 128 + tid];
  __syncthreads();
  const unsigned short* ep = encb + (size_t)b * 1048576 + (size_t)sc * 128 * 1024 + tid * 4;
  f32x4 a0 = {}, a1 = {};
  for (int s = 0; s < 128; s += 2) {
    ushort4 u0 = *(const ushort4*)(ep + (size_t)s * 1024);
    ushort4 u1 = *(const ushort4*)(ep + (size_t)(s + 1) * 1024);
    float w0 = w[s], w1 = w[s + 1];
    a0.x += w0 * bf2f(u0.x); a0.y += w0 * bf2f(u0.y);
    a0.z += w0 * bf2f(u0.z); a0.w += w0 * bf2f(u0.w);
    a1.x += w1 * bf2f(u1.x); a1.y += w1 * bf2f(u1.y);
    a1.z += w1 * bf2f(u1.z); a1.w += w1 * bf2f(u1.w);
  }
  f32x4 r = a0 + a1;
  *(f32x4*)(ctxpart + ((size_t)sc * 64 + b) * 1024 + tid * 4) = r;
}

__global__ __launch_bounds__(256) void ctx_reduce(const float* __restrict__ ctxpart,
                                                  float* __restrict__ x) {
  int idx = blockIdx.x * 256 + threadIdx.x;   // 65536
  int b = idx >> 10, e = idx & 1023;
  float s = 0.0f;
#pragma unroll
  for (int sc = 0; sc < 8; sc++) s += ctxpart[((size_t)sc * 64 + b) * 1024 + e];
  x[(size_t)b * 2048 + 1024 + e] = s;
}

// fallback fp32 context
__global__ __launch_bounds__(256) void context_k(const float* __restrict__ enc,
                                                 const float* __restrict__ attnw,
                                                 float* __restrict__ x) {
  __shared__ float w[1024];
  int b = blockIdx.y, e0 = blockIdx.x * 256, tid = threadIdx.x;
#pragma unroll
  for (int i = 0; i < 4; i++) w[tid + 256 * i] = attnw[b * 1024 + tid + 256 * i];
  __syncthreads();
  const float* ep = enc + (size_t)b * 1024 * 1024 + e0 + tid;
  float acc = 0.0f;
#pragma unroll 4
  for (int s = 0; s < 1024; s++) acc += w[s] * ep[(size_t)s * 1024];
  x[(size_t)b * 2048 + 1024 + e0 + tid] = acc;
}

__global__ __launch_bounds__(256) void cell_k(const float* __restrict__ part, int nsplit,
                                              const float* __restrict__ bih,
                                              const float* __restrict__ bhh,
                                              const float* __restrict__ cin,
                                              float* __restrict__ hout,
                                              float* __restrict__ cout) {
  int idx = blockIdx.x * 256 + threadIdx.x;
  int b = idx >> 10, h = idx & 1023;
  float gi = bih[h] + bhh[h];
  float gf = bih[1024 + h] + bhh[1024 + h];
  float gg = bih[2048 + h] + bhh[2048 + h];
  float go = bih[3072 + h] + bhh[3072 + h];
  const float* p = part + (size_t)b * 4096 + h;
  for (int sp = 0; sp < nsplit; sp++, p += 262144) {
    gi += p[0]; gf += p[1024]; gg += p[2048]; go += p[3072];
  }
  float c = sigm(gf) * cin[idx] + sigm(gi) * tanhf(gg);
  float hh = sigm(go) * tanhf(c);
  cout[idx] = c;
  hout[idx] = hh;
}

__global__ __launch_bounds__(256) void logits_reduce(const float* __restrict__ part,
                                                     const float* __restrict__ bout,
                                                     float* __restrict__ out) {
  int v = blockIdx.x * 256 + threadIdx.x;
  int b = blockIdx.y;
  size_t i = (size_t)b * 32000 + v;
  out[i] = bout[v] + part[i] + part[2048000 + i];
}

extern "C" void kernel_launch(void* const* d_in, const int* in_sizes, int n_in,
                              void* d_out, int out_size, void* d_ws, size_t ws_size,
                              hipStream_t stream) {
  const int*   input_step = (const int*)d_in[0];
  const float* h0   = (const float*)d_in[1];
  const float* c0   = (const float*)d_in[2];
  const float* enc  = (const float*)d_in[3];
  const float* emb  = (const float*)d_in[4];
  const float* Wa_h = (const float*)d_in[5];
  const float* ba_h = (const float*)d_in[6];
  const float* Wa_e = (const float*)d_in[7];
  const float* ba_e = (const float*)d_in[8];
  const float* va   = (const float*)d_in[9];
  const float* Wih0 = (const float*)d_in[11];
  const float* Whh0 = (const float*)d_in[12];
  const float* bih0 = (const float*)d_in[13];
  const float* bhh0 = (const float*)d_in[14];
  const float* Wih1 = (const float*)d_in[15];
  const float* Whh1 = (const float*)d_in[16];
  const float* bih1 = (const float*)d_in[17];
  const float* bhh1 = (const float*)d_in[18];
  const float* Wout = (const float*)d_in[19];
  const float* bout = (const float*)d_in[20];

  float* out    = (float*)d_out;
  float* logits = out;
  float* h1o    = out + 2048000;
  float* h2o    = out + 2113536;
  float* c1o    = out + 2179072;
  float* c2o    = out + 2244608;
  float* attnw  = out + 2310144;

  float* ws      = (float*)d_ws;
  float* x       = ws;
  float* q       = ws + 131072;
  float* score   = ws + 196608;
  float* part    = ws + 262144;
  float* ctxpart = ws + 4358144;
  unsigned short* Waeb = (unsigned short*)(ws + 4882432);
  unsigned short* encb = (unsigned short*)(ws + 6979584);
  const bool big = ws_size >= 162136064ull;   // 40,534,016 floats

  gather_k<<<64, 256, 0, stream>>>(input_step, emb, x);

  // q = h0[1] @ Wa_h^T
  small_gemm<<<dim3(4, 8), 256, 0, stream>>>(
      h0 + 65536, 1024, h0 + 65536, 1024, 1024,
      Wa_h, 1024, Wa_h, 1024, 1024,
      part, 1024, 128);
  q_reduce<<<256, 256, 0, stream>>>(part, ba_h, q);

  hipMemsetAsync(score, 0, 65536 * sizeof(float), stream);

  if (big) {
    cvt_bf_k<<<512, 256, 0, stream>>>(Wa_e, Waeb, 131072);      // 1,048,576/8
    cvt_bf_k<<<32768, 256, 0, stream>>>(enc, encb, 8388608);    // 67,108,864/8
    attn_gemm_8p<<<dim3(4, 256), 512, 0, stream>>>(encb, Waeb, q, ba_e, va, score);
    softmax_k<<<64, 256, 0, stream>>>(score, attnw);
    context_bf<<<dim3(64, 8), 256, 0, stream>>>(encb, attnw, ctxpart);
    ctx_reduce<<<256, 256, 0, stream>>>(ctxpart, x);
  } else {
    attn_gemm_f32<<<dim3(4, 512), 512, 0, stream>>>(enc, Wa_e, q, ba_e, va, score);
    softmax_k<<<64, 256, 0, stream>>>(score, attnw);
    context_k<<<dim3(4, 64), 256, 0, stream>>>(enc, attnw, x);
  }

  // LSTM layer 0
  small_gemm<<<dim3(16, 12), 256, 0, stream>>>(
      x, 2048, h0, 1024, 2048,
      Wih0, 2048, Whh0, 1024, 2048,
      part, 4096, 256);
  cell_k<<<256, 256, 0, stream>>>(part, 12, bih0, bhh0, c0, h1o, c1o);

  // LSTM layer 1
  small_gemm<<<dim3(16, 8), 256, 0, stream>>>(
      h1o, 1024, h0 + 65536, 1024, 1024,
      Wih1, 1024, Whh1, 1024, 1024,
      part, 4096, 256);
  cell_k<<<256, 256, 0, stream>>>(part, 8, bih1, bhh1, c0 + 65536, h2o, c2o);

  // logits
  small_gemm<<<dim3(125, 2), 256, 0, stream>>>(
      h2o, 1024, h2o, 1024, 1024,
      Wout, 1024, Wout, 1024, 1024,
      part, 32000, 512);
  logits_reduce<<<dim3(125, 64), 256, 0, stream>>>(part, bout, logits);
}

// Round 2
// 854.873 us; speedup vs baseline: 1.0146x; 1.0146x over previous
//
#include <hip/hip_runtime.h>

// Decoder step: attention (Bahdanau) + 2-layer LSTM + vocab projection.
// B=64, S=1024, V=32000, D=H=E=A=1024, L=2.
//
// d_out (floats): logits[64*32000] | h_new[2*64*1024] | c_new[2*64*1024] | attn_w[64*1024]
// ws (floats), big path (needs 162,136,064 B):
//   x[64*2048]@0 | q@131072 | score@196608 | part@262144 (max 4,096,000)
//   ctxpart@4358144 (8*64*1024) | Wae_bf16@4882432 (1,048,576 ushorts) | enc_bf16@6979584
// bva dropped: softmax(score+bva)==softmax(score).
//
// R2 (this round): attn GEMM schedule fixed per m196/m218 evidence.
// R1's coarse staging (8 gloads clumped at P3, vmcnt(8) 2-deep) + 2 barriers
// per phase measured 642 TF (phase ~2000cy vs 154cy MFMA content). Now:
// spread staging 2 gloads/phase in dependency order (A-lo,B01,B23,A-hi),
// counted waits vmcnt(4)@P1 / vmcnt(2)@P3 (never 0 in steady state), and
// ONE barrier per phase: [stage; ds_reads; vmcnt?; bar; lgkm0; MFMA].
// WAR safety: each stage-write hits LDS chunks whose reads drained >=3
// barrier-crossings earlier; RAW: all waves vmcnt before common barrier.

typedef __attribute__((ext_vector_type(8))) __bf16 bf16x8;
typedef __attribute__((ext_vector_type(4))) __bf16 bf16x4v;
typedef __attribute__((ext_vector_type(4))) float f32x4;

#define GLOADLDS(g, l)                                                         \
  __builtin_amdgcn_global_load_lds(                                            \
      (const __attribute__((address_space(1))) unsigned int*)(g),              \
      (__attribute__((address_space(3))) unsigned int*)(l), 16, 0, 0)

__device__ __forceinline__ ushort4 cvt4(f32x4 v) {
  bf16x4v h = {(__bf16)v.x, (__bf16)v.y, (__bf16)v.z, (__bf16)v.w};  // RNE; native cvt_pk on gfx950
  union { bf16x4v h; ushort4 u; } c; c.h = h; return c.u;
}
__device__ __forceinline__ float bf2f(unsigned short u) {
  return __uint_as_float(((unsigned int)u) << 16);
}
__device__ __forceinline__ float sigm(float x) { return 1.0f / (1.0f + __expf(-x)); }
// exact at both limits: x->+inf => 1-0 ; x->-inf => 1-2 = -1
__device__ __forceinline__ float fast_tanh(float x) {
  return 1.0f - 2.0f / (__expf(2.0f * x) + 1.0f);
}

// fp32 -> bf16, 8 elements/thread; n8 = element_count / 8
__global__ __launch_bounds__(256) void cvt_bf_k(const float* __restrict__ in,
                                                unsigned short* __restrict__ out, int n8) {
  int i = blockIdx.x * 256 + threadIdx.x;
  if (i >= n8) return;
  const f32x4* p = (const f32x4*)in + 2 * (size_t)i;
  ushort4* o = (ushort4*)out + 2 * (size_t)i;
  f32x4 a = p[0], b = p[1];
  o[0] = cvt4(a);
  o[1] = cvt4(b);
}

// x[b][0:1024] = emb[input_step[b]]
__global__ __launch_bounds__(256) void gather_k(const int* __restrict__ step,
                                                const float* __restrict__ emb,
                                                float* __restrict__ x) {
  int b = blockIdx.x, t = threadIdx.x;
  int row = step[b];
  f32x4 v = *(const f32x4*)(emb + (size_t)row * 1024 + t * 4);
  *(f32x4*)(x + (size_t)b * 2048 + t * 4) = v;
}

// Split-K skinny GEMM, M=64, BN=256, fp32 in, bf16 staging via native casts.
__global__ __launch_bounds__(256) void small_gemm(
    const float* __restrict__ A0, int lda0,
    const float* __restrict__ A1, int lda1, int kSplitA,
    const float* __restrict__ B0, int ldb0,
    const float* __restrict__ B1, int ldb1, int kSplitB,
    float* __restrict__ part, int N, int kChunk) {
  __shared__ unsigned short As[64 * 32];
  __shared__ unsigned short Bs[256 * 32];
  int tid = threadIdx.x;
  int n0 = blockIdx.x * 256;
  int k0 = blockIdx.y * kChunk;
  int wave = tid >> 6, lane = tid & 63, quad = lane >> 4, l15 = lane & 15;
  f32x4 acc[4][4] = {};
  for (int kb = k0; kb < k0 + kChunk; kb += 32) {
    const float* Ap; int ldA, kA;
    if (kb < kSplitA) { Ap = A0; ldA = lda0; kA = kb; }
    else              { Ap = A1; ldA = lda1; kA = kb - kSplitA; }
    const float* Bp; int ldB, kB;
    if (kb < kSplitB) { Bp = B0; ldB = ldb0; kB = kb; }
    else              { Bp = B1; ldB = ldb1; kB = kb - kSplitB; }
#pragma unroll
    for (int c = 0; c < 2; c++) {               // A: 64x32
      int f = c * 256 + tid;
      int row = f >> 3, colf = f & 7;
      f32x4 v = *(const f32x4*)(Ap + (size_t)row * ldA + kA + colf * 4);
      *(ushort4*)&As[row * 32 + colf * 4] = cvt4(v);
    }
#pragma unroll
    for (int c = 0; c < 8; c++) {               // B: 256x32
      int f = c * 256 + tid;
      int row = f >> 3, colf = f & 7;
      f32x4 v = *(const f32x4*)(Bp + (size_t)(n0 + row) * ldB + kB + colf * 4);
      *(ushort4*)&Bs[row * 32 + colf * 4] = cvt4(v);
    }
    __syncthreads();
    bf16x8 af[4], bfv[4];
#pragma unroll
    for (int rt = 0; rt < 4; rt++)
      af[rt] = *(const bf16x8*)&As[(16 * rt + l15) * 32 + quad * 8];
#pragma unroll
    for (int ct = 0; ct < 4; ct++)
      bfv[ct] = *(const bf16x8*)&Bs[(64 * wave + 16 * ct + l15) * 32 + quad * 8];
#pragma unroll
    for (int rt = 0; rt < 4; rt++)
#pragma unroll
      for (int ct = 0; ct < 4; ct++)
        acc[rt][ct] = __builtin_amdgcn_mfma_f32_16x16x32_bf16(af[rt], bfv[ct], acc[rt][ct], 0, 0, 0);
    __syncthreads();
  }
  size_t base = (size_t)blockIdx.y * 64 * (size_t)N;
#pragma unroll
  for (int rt = 0; rt < 4; rt++)
#pragma unroll
    for (int ct = 0; ct < 4; ct++)
#pragma unroll
      for (int r = 0; r < 4; r++) {
        int m = 16 * rt + 4 * quad + r;
        int n = n0 + 64 * wave + 16 * ct + l15;
        part[base + (size_t)m * N + n] = acc[rt][ct][r];
      }
}

// q[b][a] = ba_h[a] + sum over 8 k-splits
__global__ __launch_bounds__(256) void q_reduce(const float* __restrict__ qpart,
                                                const float* __restrict__ ba_h,
                                                float* __restrict__ q) {
  int idx = blockIdx.x * 256 + threadIdx.x;
  int a = idx & 1023;
  float s = ba_h[a];
#pragma unroll
  for (int sp = 0; sp < 8; sp++) s += qpart[sp * 65536 + idx];
  q[idx] = s;
}

// ---------------------------------------------------------------------------
// 8-wave 256x256x64 bf16 attention GEMM, fused Bahdanau score epilogue.
// M=65536 N=1024 K=1024. 512 thr = 8 waves (2M x 4N), 128x64 out/wave.
// LDS: 2 buffers x (A 32KB + B 32KB) = 128KB, column-XOR-swizzled.
// Per K-tile, 4 phases; each phase: [stage 2 gloads of tile c+1] [ds_reads]
// [counted vmcnt at P1/P3] [s_barrier] [lgkmcnt(0)] [setprio1 16xMFMA].
// Stage order A-lo,B01,B23,A-hi; vmcnt(4)@P1 drains A-hi(c) (2-phase lead),
// vmcnt(2)@P3 drains the 6 loads tile c+1's P0 needs (leaves A-hi(c+1)).
// ---------------------------------------------------------------------------

#define SCHED0() __builtin_amdgcn_sched_barrier(0)
#define VMCNT(n) asm volatile("s_waitcnt vmcnt(" #n ")" ::: "memory")

// A chunks: j covers rows [64j,64j+64). lo = j0,j2 (read at P0), hi = j1,j3 (P2).
#define STAGE_A2(bufv, t, j0v, j1v)                                          \
  {                                                                          \
    const unsigned short* _s = encb + aSrc + (size_t)(t) * 64;               \
    unsigned short* _l = &sh[(bufv) * 32768 + wave * 512];                   \
    GLOADLDS(_s + (j0v) * 65536, _l + (j0v) * 4096);                         \
    GLOADLDS(_s + (j1v) * 65536, _l + (j1v) * 4096);                         \
  }
#define STAGE_B2(bufv, t, j0v, j1v)                                          \
  {                                                                          \
    const unsigned short* _s = Waeb + bSrc + (size_t)(t) * 64;               \
    unsigned short* _l = &sh[(bufv) * 32768 + 16384 + wave * 512];           \
    GLOADLDS(_s + (j0v) * 65536, _l + (j0v) * 4096);                         \
    GLOADLDS(_s + (j1v) * 65536, _l + (j1v) * 4096);                         \
  }

#define LOAD_A(buf, mh)                                                      \
  {                                                                          \
    const unsigned short* _p = &sh[(buf) * 32768 + aRow + (mh) * 4096];      \
    _Pragma("unroll") for (int mr = 0; mr < 4; mr++) {                       \
      a[mr][0] = *(const bf16x8*)&_p[mr * 1024 + cs0];                       \
      a[mr][1] = *(const bf16x8*)&_p[mr * 1024 + cs1];                       \
    }                                                                        \
  }

#define LOAD_B(buf, nh, Bd)                                                  \
  {                                                                          \
    const unsigned short* _p = &sh[(buf) * 32768 + 16384 + bRow + (nh) * 2048]; \
    _Pragma("unroll") for (int nc = 0; nc < 2; nc++) {                       \
      Bd[nc][0] = *(const bf16x8*)&_p[nc * 1024 + cs0];                      \
      Bd[nc][1] = *(const bf16x8*)&_p[nc * 1024 + cs1];                      \
    }                                                                        \
  }

#define MMQ(mh, nh, Bd)                                                      \
  _Pragma("unroll") for (int mr = 0; mr < 4; mr++)                           \
  _Pragma("unroll") for (int nc = 0; nc < 2; nc++)                           \
  _Pragma("unroll") for (int ks = 0; ks < 2; ks++)                           \
    acc[(mh) * 4 + mr][(nh) * 2 + nc] = __builtin_amdgcn_mfma_f32_16x16x32_bf16( \
        a[mr][ks], Bd[nc][ks], acc[(mh) * 4 + mr][(nh) * 2 + nc], 0, 0, 0);

#define PHASE_SYNC()                                                         \
  SCHED0();                                                                  \
  __builtin_amdgcn_s_barrier();                                              \
  asm volatile("s_waitcnt lgkmcnt(0)" ::: "memory");                         \
  SCHED0();

#define P_MFMA(mh, nh, Bd)                                                   \
  __builtin_amdgcn_s_setprio(1); MMQ(mh, nh, Bd); __builtin_amdgcn_s_setprio(0); \
  SCHED0();

// Steady-state group: computes tile c from buf, stages tile c+1 into buf^1.
#define GROUP_MAIN(c)                                                        \
  {                                                                          \
    int buf = (c) & 1, nbuf = buf ^ 1;                                       \
    /* P0 */                                                                 \
    STAGE_A2(nbuf, (c) + 1, 0, 2);                                           \
    LOAD_A(buf, 0);                                                          \
    LOAD_B(buf, 0, b0);                                                      \
    PHASE_SYNC();                                                            \
    P_MFMA(0, 0, b0);                                                        \
    /* P1 */                                                                 \
    STAGE_B2(nbuf, (c) + 1, 0, 1);                                           \
    LOAD_B(buf, 1, b1);                                                      \
    VMCNT(4);            /* drain A-hi(c), staged 2 phases ago */            \
    PHASE_SYNC();                                                            \
    P_MFMA(0, 1, b1);                                                        \
    /* P2 */                                                                 \
    STAGE_B2(nbuf, (c) + 1, 2, 3);                                           \
    LOAD_A(buf, 1);                                                          \
    PHASE_SYNC();                                                            \
    P_MFMA(1, 0, b0);                                                        \
    /* P3 */                                                                 \
    STAGE_A2(nbuf, (c) + 1, 1, 3);                                           \
    VMCNT(2);            /* drain A-lo+B(c+1); leave A-hi(c+1) in flight */  \
    PHASE_SYNC();                                                            \
    P_MFMA(1, 1, b1);                                                        \
  }

// Last tile (c=15): no staging; P1 drains the final A-hi.
#define GROUP_TAIL(c)                                                        \
  {                                                                          \
    int buf = (c) & 1;                                                       \
    LOAD_A(buf, 0);                                                          \
    LOAD_B(buf, 0, b0);                                                      \
    PHASE_SYNC();                                                            \
    P_MFMA(0, 0, b0);                                                        \
    LOAD_B(buf, 1, b1);                                                      \
    VMCNT(0);            /* drain A-hi(15), staged 2 phases ago */           \
    PHASE_SYNC();                                                            \
    P_MFMA(0, 1, b1);                                                        \
    LOAD_A(buf, 1);                                                          \
    PHASE_SYNC();                                                            \
    P_MFMA(1, 0, b0);                                                        \
    PHASE_SYNC();                                                            \
    P_MFMA(1, 1, b1);                                                        \
  }

__global__ __launch_bounds__(512, 2) void attn_gemm_8p(
    const unsigned short* __restrict__ encb, const unsigned short* __restrict__ Waeb,
    const float* __restrict__ q, const float* __restrict__ ba_e,
    const float* __restrict__ va, float* __restrict__ score) {
  __shared__ unsigned short sh[65536];   // [2 bufs][A 16384 | B 16384] ushorts
  __shared__ float red[256];
  int tid = threadIdx.x;
  int wave = tid >> 6, lane = tid & 63, quad = lane >> 4, l15 = lane & 15;
  int wr = wave >> 2, wc = wave & 3;

  // XCD swizzle: hw linear id -> logical; 4 N-siblings of an M-tile land on
  // one XCD so the 512KB A-panel is fetched once into that XCD's L2.
  int h = blockIdx.y * 4 + blockIdx.x;          // 0..1023, x-fastest dispatch
  int lgc = (h & 7) * 128 + (h >> 3);           // bijective, 1024 % 8 == 0
  int m0 = (lgc >> 2) * 256, n0 = (lgc & 3) * 256;

  // Staging source (pre-swizzled): dest byte p = j*8192 + wave*1024 + lane*16
  // holds logical element at p ^ ((p>>3)&0x70)  (row unchanged; 16B slot
  // slot = (lane&7) ^ (lane>>3) since row&7 == lane>>3 here).
  int srow = wave * 8 + (lane >> 3);
  int sslot = ((lane & 7) ^ (lane >> 3)) * 8;
  size_t aSrc = (size_t)(m0 + srow) * 1024 + sslot;
  size_t bSrc = (size_t)(n0 + srow) * 1024 + sslot;

  // Fragment read offsets (ushorts): logical u = row*64 + ks*32 + quad*8,
  // swizzled u ^= (u>>3)&0x38  ==  slot' = (ks*4+quad) ^ (l15&7).
  int aRow = (wr * 128 + l15) * 64;
  int bRow = (wc * 64 + l15) * 64;
  int cs0 = (quad ^ (l15 & 7)) * 8;
  int cs1 = ((4 + quad) ^ (l15 & 7)) * 8;

  bf16x8 a[4][2], b0[2][2], b1[2][2];
  f32x4 acc[8][4] = {};

  // Prologue: stage tile 0 fully (order A-lo,B01,B23,A-hi), drain all but
  // A-hi (vmcnt(2)); A-hi(0) is drained by GROUP_MAIN(0)'s P1 vmcnt(4).
  STAGE_A2(0, 0, 0, 2);
  STAGE_B2(0, 0, 0, 1);
  STAGE_B2(0, 0, 2, 3);
  STAGE_A2(0, 0, 1, 3);
  VMCNT(2);
  SCHED0();
  __builtin_amdgcn_s_barrier();
  SCHED0();

#pragma unroll 1
  for (int c = 0; c < 15; ++c) GROUP_MAIN(c);
  GROUP_TAIL(15);

  // ---- fused score epilogue: score[m] += sum_n va[n]*tanh(q+ba_e+C[m,n]) ----
  __syncthreads();
  if (tid < 256) red[tid] = 0.0f;
  __syncthreads();
  int b = m0 >> 10;
  float qe[4], vv[4];
#pragma unroll
  for (int j = 0; j < 4; j++) {
    int n = n0 + wc * 64 + j * 16 + l15;
    qe[j] = q[b * 1024 + n] + ba_e[n];
    vv[j] = va[n];
  }
#pragma unroll
  for (int i = 0; i < 8; i++)
#pragma unroll
    for (int r = 0; r < 4; r++) {
      float p = 0.0f;
#pragma unroll
      for (int j = 0; j < 4; j++)
        p += vv[j] * fast_tanh(qe[j] + acc[i][j][r]);
      p += __shfl_xor(p, 1); p += __shfl_xor(p, 2);
      p += __shfl_xor(p, 4); p += __shfl_xor(p, 8);
      if (l15 == 0) atomicAdd(&red[wr * 128 + i * 16 + quad * 4 + r], p);
    }
  __syncthreads();
  if (tid < 256) atomicAdd(&score[m0 + tid], red[tid]);
}

#undef GROUP_TAIL
#undef GROUP_MAIN
#undef P_MFMA
#undef PHASE_SYNC
#undef MMQ
#undef LOAD_B
#undef LOAD_A
#undef STAGE_B2
#undef STAGE_A2
#undef VMCNT
#undef SCHED0

// fallback fp32 attention GEMM (grid dim3(4,512), N-fastest)
__global__ __launch_bounds__(512) void attn_gemm_f32(
    const float* __restrict__ enc, const float* __restrict__ Wae,
    const float* __restrict__ q, const float* __restrict__ ba_e,
    const float* __restrict__ va, float* __restrict__ score) {
  __shared__ unsigned short As[128 * 32];
  __shared__ unsigned short Bs[256 * 32];
  __shared__ float red[128];
  int tid = threadIdx.x;
  int n0 = blockIdx.x * 256, m0 = blockIdx.y * 128;
  int wave = tid >> 6, lane = tid & 63, quad = lane >> 4, l15 = lane & 15;
  int wr = wave >> 2, wc = wave & 3;
  f32x4 acc[4][4] = {};
  for (int kb = 0; kb < 1024; kb += 32) {
#pragma unroll
    for (int c = 0; c < 2; c++) {
      int f = c * 512 + tid;
      int row = f >> 3, colf = f & 7;
      f32x4 v = *(const f32x4*)(enc + (size_t)(m0 + row) * 1024 + kb + colf * 4);
      *(ushort4*)&As[row * 32 + colf * 4] = cvt4(v);
    }
#pragma unroll
    for (int c = 0; c < 4; c++) {
      int f = c * 512 + tid;
      int row = f >> 3, colf = f & 7;
      f32x4 v = *(const f32x4*)(Wae + (size_t)(n0 + row) * 1024 + kb + colf * 4);
      *(ushort4*)&Bs[row * 32 + colf * 4] = cvt4(v);
    }
    __syncthreads();
    bf16x8 af[4], bfv[4];
#pragma unroll
    for (int rt = 0; rt < 4; rt++)
      af[rt] = *(const bf16x8*)&As[(64 * wr + 16 * rt + l15) * 32 + quad * 8];
#pragma unroll
    for (int ct = 0; ct < 4; ct++)
      bfv[ct] = *(const bf16x8*)&Bs[(64 * wc + 16 * ct + l15) * 32 + quad * 8];
#pragma unroll
    for (int rt = 0; rt < 4; rt++)
#pragma unroll
      for (int ct = 0; ct < 4; ct++)
        acc[rt][ct] = __builtin_amdgcn_mfma_f32_16x16x32_bf16(af[rt], bfv[ct], acc[rt][ct], 0, 0, 0);
    __syncthreads();
  }
  int b = m0 >> 10;
  if (tid < 128) red[tid] = 0.0f;
  __syncthreads();
  float qe[4], vv[4];
#pragma unroll
  for (int ct = 0; ct < 4; ct++) {
    int n = n0 + 64 * wc + 16 * ct + l15;
    qe[ct] = q[b * 1024 + n] + ba_e[n];
    vv[ct] = va[n];
  }
#pragma unroll
  for (int rt = 0; rt < 4; rt++)
#pragma unroll
    for (int r = 0; r < 4; r++) {
      float p = 0.0f;
#pragma unroll
      for (int ct = 0; ct < 4; ct++)
        p += vv[ct] * tanhf(qe[ct] + acc[rt][ct][r]);
      p += __shfl_xor(p, 1); p += __shfl_xor(p, 2);
      p += __shfl_xor(p, 4); p += __shfl_xor(p, 8);
      if (l15 == 0) atomicAdd(&red[64 * wr + 16 * rt + 4 * quad + r], p);
    }
  __syncthreads();
  if (tid < 128) atomicAdd(&score[m0 + tid], red[tid]);
}

__global__ __launch_bounds__(256) void softmax_k(const float* __restrict__ score,
                                                 float* __restrict__ attnw) {
  int b = blockIdx.x, tid = threadIdx.x;
  __shared__ float wred[4];
  float v[4];
  float mx = -1e30f;
#pragma unroll
  for (int i = 0; i < 4; i++) {
    v[i] = score[b * 1024 + tid + 256 * i];
    mx = fmaxf(mx, v[i]);
  }
  for (int off = 1; off < 64; off <<= 1) mx = fmaxf(mx, __shfl_xor(mx, off));
  int w = tid >> 6;
  if ((tid & 63) == 0) wred[w] = mx;
  __syncthreads();
  mx = fmaxf(fmaxf(wred[0], wred[1]), fmaxf(wred[2], wred[3]));
  float s = 0.0f;
#pragma unroll
  for (int i = 0; i < 4; i++) { v[i] = __expf(v[i] - mx); s += v[i]; }
  for (int off = 1; off < 64; off <<= 1) s += __shfl_xor(s, off);
  __syncthreads();
  if ((tid & 63) == 0) wred[w] = s;
  __syncthreads();
  s = wred[0] + wred[1] + wred[2] + wred[3];
  float inv = 1.0f / s;
#pragma unroll
  for (int i = 0; i < 4; i++) attnw[b * 1024 + tid + 256 * i] = v[i] * inv;
}

// context partial over s-chunks (bf16 enc): grid (64 b, 8 sc), thread owns 4 e
__global__ __launch_bounds__(256) void context_bf(const unsigned short* __restrict__ encb,
                                                  const float* __restrict__ attnw,
                                                  float* __restrict__ ctxpart) {
  int b = blockIdx.x, sc = blockIdx.y, tid = threadIdx.x;
  __shared__ float w[128];
  if (tid < 128) w[tid] = attnw[b * 1024 + sc * 128 + tid];
  __syncthreads();
  const unsigned short* ep = encb + (size_t)b * 1048576 + (size_t)sc * 128 * 1024 + tid * 4;
  f32x4 a0 = {}, a1 = {};
  for (int s = 0; s < 128; s += 2) {
    ushort4 u0 = *(const ushort4*)(ep + (size_t)s * 1024);
    ushort4 u1 = *(const ushort4*)(ep + (size_t)(s + 1) * 1024);
    float w0 = w[s], w1 = w[s + 1];
    a0.x += w0 * bf2f(u0.x); a0.y += w0 * bf2f(u0.y);
    a0.z += w0 * bf2f(u0.z); a0.w += w0 * bf2f(u0.w);
    a1.x += w1 * bf2f(u1.x); a1.y += w1 * bf2f(u1.y);
    a1.z += w1 * bf2f(u1.z); a1.w += w1 * bf2f(u1.w);
  }
  f32x4 r = a0 + a1;
  *(f32x4*)(ctxpart + ((size_t)sc * 64 + b) * 1024 + tid * 4) = r;
}

__global__ __launch_bounds__(256) void ctx_reduce(const float* __restrict__ ctxpart,
                                                  float* __restrict__ x) {
  int idx = blockIdx.x * 256 + threadIdx.x;   // 65536
  int b = idx >> 10, e = idx & 1023;
  float s = 0.0f;
#pragma unroll
  for (int sc = 0; sc < 8; sc++) s += ctxpart[((size_t)sc * 64 + b) * 1024 + e];
  x[(size_t)b * 2048 + 1024 + e] = s;
}

// fallback fp32 context
__global__ __launch_bounds__(256) void context_k(const float* __restrict__ enc,
                                                 const float* __restrict__ attnw,
                                                 float* __restrict__ x) {
  __shared__ float w[1024];
  int b = blockIdx.y, e0 = blockIdx.x * 256, tid = threadIdx.x;
#pragma unroll
  for (int i = 0; i < 4; i++) w[tid + 256 * i] = attnw[b * 1024 + tid + 256 * i];
  __syncthreads();
  const float* ep = enc + (size_t)b * 1024 * 1024 + e0 + tid;
  float acc = 0.0f;
#pragma unroll 4
  for (int s = 0; s < 1024; s++) acc += w[s] * ep[(size_t)s * 1024];
  x[(size_t)b * 2048 + 1024 + e0 + tid] = acc;
}

__global__ __launch_bounds__(256) void cell_k(const float* __restrict__ part, int nsplit,
                                              const float* __restrict__ bih,
                                              const float* __restrict__ bhh,
                                              const float* __restrict__ cin,
                                              float* __restrict__ hout,
                                              float* __restrict__ cout) {
  int idx = blockIdx.x * 256 + threadIdx.x;
  int b = idx >> 10, h = idx & 1023;
  float gi = bih[h] + bhh[h];
  float gf = bih[1024 + h] + bhh[1024 + h];
  float gg = bih[2048 + h] + bhh[2048 + h];
  float go = bih[3072 + h] + bhh[3072 + h];
  const float* p = part + (size_t)b * 4096 + h;
  for (int sp = 0; sp < nsplit; sp++, p += 262144) {
    gi += p[0]; gf += p[1024]; gg += p[2048]; go += p[3072];
  }
  float c = sigm(gf) * cin[idx] + sigm(gi) * tanhf(gg);
  float hh = sigm(go) * tanhf(c);
  cout[idx] = c;
  hout[idx] = hh;
}

__global__ __launch_bounds__(256) void logits_reduce(const float* __restrict__ part,
                                                     const float* __restrict__ bout,
                                                     float* __restrict__ out) {
  int v = blockIdx.x * 256 + threadIdx.x;
  int b = blockIdx.y;
  size_t i = (size_t)b * 32000 + v;
  out[i] = bout[v] + part[i] + part[2048000 + i];
}

extern "C" void kernel_launch(void* const* d_in, const int* in_sizes, int n_in,
                              void* d_out, int out_size, void* d_ws, size_t ws_size,
                              hipStream_t stream) {
  const int*   input_step = (const int*)d_in[0];
  const float* h0   = (const float*)d_in[1];
  const float* c0   = (const float*)d_in[2];
  const float* enc  = (const float*)d_in[3];
  const float* emb  = (const float*)d_in[4];
  const float* Wa_h = (const float*)d_in[5];
  const float* ba_h = (const float*)d_in[6];
  const float* Wa_e = (const float*)d_in[7];
  const float* ba_e = (const float*)d_in[8];
  const float* va   = (const float*)d_in[9];
  const float* Wih0 = (const float*)d_in[11];
  const float* Whh0 = (const float*)d_in[12];
  const float* bih0 = (const float*)d_in[13];
  const float* bhh0 = (const float*)d_in[14];
  const float* Wih1 = (const float*)d_in[15];
  const float* Whh1 = (const float*)d_in[16];
  const float* bih1 = (const float*)d_in[17];
  const float* bhh1 = (const float*)d_in[18];
  const float* Wout = (const float*)d_in[19];
  const float* bout = (const float*)d_in[20];

  float* out    = (float*)d_out;
  float* logits = out;
  float* h1o    = out + 2048000;
  float* h2o    = out + 2113536;
  float* c1o    = out + 2179072;
  float* c2o    = out + 2244608;
  float* attnw  = out + 2310144;

  float* ws      = (float*)d_ws;
  float* x       = ws;
  float* q       = ws + 131072;
  float* score   = ws + 196608;
  float* part    = ws + 262144;
  float* ctxpart = ws + 4358144;
  unsigned short* Waeb = (unsigned short*)(ws + 4882432);
  unsigned short* encb = (unsigned short*)(ws + 6979584);
  const bool big = ws_size >= 162136064ull;   // 40,534,016 floats

  gather_k<<<64, 256, 0, stream>>>(input_step, emb, x);

  // q = h0[1] @ Wa_h^T
  small_gemm<<<dim3(4, 8), 256, 0, stream>>>(
      h0 + 65536, 1024, h0 + 65536, 1024, 1024,
      Wa_h, 1024, Wa_h, 1024, 1024,
      part, 1024, 128);
  q_reduce<<<256, 256, 0, stream>>>(part, ba_h, q);

  hipMemsetAsync(score, 0, 65536 * sizeof(float), stream);

  if (big) {
    cvt_bf_k<<<512, 256, 0, stream>>>(Wa_e, Waeb, 131072);      // 1,048,576/8
    cvt_bf_k<<<32768, 256, 0, stream>>>(enc, encb, 8388608);    // 67,108,864/8
    attn_gemm_8p<<<dim3(4, 256), 512, 0, stream>>>(encb, Waeb, q, ba_e, va, score);
    softmax_k<<<64, 256, 0, stream>>>(score, attnw);
    context_bf<<<dim3(64, 8), 256, 0, stream>>>(encb, attnw, ctxpart);
    ctx_reduce<<<256, 256, 0, stream>>>(ctxpart, x);
  } else {
    attn_gemm_f32<<<dim3(4, 512), 512, 0, stream>>>(enc, Wa_e, q, ba_e, va, score);
    softmax_k<<<64, 256, 0, stream>>>(score, attnw);
    context_k<<<dim3(4, 64), 256, 0, stream>>>(enc, attnw, x);
  }

  // LSTM layer 0
  small_gemm<<<dim3(16, 12), 256, 0, stream>>>(
      x, 2048, h0, 1024, 2048,
      Wih0, 2048, Whh0, 1024, 2048,
      part, 4096, 256);
  cell_k<<<256, 256, 0, stream>>>(part, 12, bih0, bhh0, c0, h1o, c1o);

  // LSTM layer 1
  small_gemm<<<dim3(16, 8), 256, 0, stream>>>(
      h1o, 1024, h0 + 65536, 1024, 1024,
      Wih1, 1024, Whh1, 1024, 1024,
      part, 4096, 256);
  cell_k<<<256, 256, 0, stream>>>(part, 8, bih1, bhh1, c0 + 65536, h2o, c2o);

  // logits
  small_gemm<<<dim3(125, 2), 256, 0, stream>>>(
      h2o, 1024, h2o, 1024, 1024,
      Wout, 1024, Wout, 1024, 1024,
      part, 32000, 512);
  logits_reduce<<<dim3(125, 64), 256, 0, stream>>>(part, bout, logits);
}